// Round 4
// baseline (420.121 us; speedup 1.0000x reference)
//
#include <hip/hip_runtime.h>
#include <math.h>

#define NB 4
#define NC 64
#define NL 1024   // 32x32 kernel-patch grid
#define NP 3969   // 63x63 correlation positions
#define PHW 63

typedef unsigned short ushort_t;
typedef __attribute__((ext_vector_type(8))) short short8;
typedef __attribute__((ext_vector_type(16))) float floatx16;

// A' per b: 32 rtiles * 64 kchunks * 64 lanes * 8 = 2^20 ushorts
#define A_BSTRIDE 1048576
// B' per b: 126 rtiles (4032 rows, padded) * 64 * 64 * 8
#define B_BSTRIDE 4128768

// ---------------- kernel 1: per-(b,c) inverse L2 norm of b ----------------
__global__ __launch_bounds__(256) void norm_kernel(const float* __restrict__ bsrc,
                                                   float* __restrict__ invn) {
    int bc = blockIdx.x;  // 0..255
    const float* src = bsrc + (size_t)bc * 4096;
    float s = 0.f;
    for (int i = threadIdx.x; i < 4096; i += 256) { float v = src[i]; s += v * v; }
#pragma unroll
    for (int off = 32; off > 0; off >>= 1) s += __shfl_down(s, off, 64);
    __shared__ float part[4];
    if ((threadIdx.x & 63) == 0) part[threadIdx.x >> 6] = s;
    __syncthreads();
    if (threadIdx.x == 0) {
        float t = part[0] + part[1] + part[2] + part[3];
        invn[bc] = 1.0f / sqrtf(t + 1e-8f);
    }
}

// ---------------- kernel 2: patch means of (1-mask) -----------------------
__global__ __launch_bounds__(256) void stats_kernel(const float* __restrict__ mask,
                                                    float* __restrict__ mmk,
                                                    float* __restrict__ mmp) {
    int id = blockIdx.x * 256 + threadIdx.x;
    if (id < NB * NL) {
        int b = id >> 10, l = id & 1023;
        int lh = l >> 5, lw = l & 31;
        const float* m = mask + b * 4096;
        float s = 0.f;
#pragma unroll
        for (int i = 0; i < 4; ++i) {
            int r = min(max(2 * lh - 1 + i, 0), 63);
#pragma unroll
            for (int j = 0; j < 4; ++j) {
                int c = min(max(2 * lw - 1 + j, 0), 63);
                s += 1.0f - m[r * 64 + c];
            }
        }
        mmk[id] = s * (1.0f / 16.0f);
    } else {
        int id2 = id - NB * NL;
        if (id2 < NB * NP) {
            int b = id2 / NP, p = id2 - b * NP;
            int ph = p / PHW, pw = p - ph * PHW;
            const float* m = mask + b * 4096;
            float s = 0.f;
#pragma unroll
            for (int i = 0; i < 4; ++i) {
                int r = min(max(ph - 1 + i, 0), 63);
#pragma unroll
                for (int j = 0; j < 4; ++j) {
                    int c = min(max(pw - 1 + j, 0), 63);
                    s += 1.0f - m[r * 64 + c];
                }
            }
            mmp[id2] = s * (1.0f / 16.0f);
        }
    }
}

// ------------- split helper: fp32 -> bf16 hi + bf16 residual --------------
__device__ inline void split_bf16(float v, ushort_t& hv, ushort_t& lv) {
    unsigned u = __float_as_uint(v);
    unsigned rr = u + 0x7FFFu + ((u >> 16) & 1u);
    hv = (ushort_t)(rr >> 16);
    float fh = __uint_as_float(((unsigned)hv) << 16);
    float remv = v - fh;
    unsigned u2 = __float_as_uint(remv);
    unsigned rr2 = u2 + 0x7FFFu + ((u2 >> 16) & 1u);
    lv = (ushort_t)(rr2 >> 16);
}

// fragment-order address for (row, kchunk): row tile of 32, 16 k per chunk.
// idx = ((row>>5)*64 + kc)*512 + (row&31)*8  (k 0..7); +256 for k 8..15.
__device__ inline int frag_addr(int row, int kc) {
    return ((row >> 5) * 64 + kc) * 512 + (row & 31) * 8;
}

// ---------------- kernel 3a: split A into fragment order ------------------
// block = (lh, b, chalf): stage 4 b-rows x 32 c into LDS, emit 32 lw x 32 c.
__global__ __launch_bounds__(256) void splitA_kernel(const float* __restrict__ bsrc,
                                                     const float* __restrict__ invn,
                                                     ushort_t* __restrict__ Ahi,
                                                     ushort_t* __restrict__ Alo) {
    __shared__ float fl[32 * 257];
    int lh = blockIdx.x, b = blockIdx.y, chalf = blockIdx.z;
    int t = threadIdx.x;
#pragma unroll
    for (int q = 0; q < 32; ++q) {
        int idx = t + (q << 8);
        int cl = idx >> 8, rem = idx & 255;
        int i = rem >> 6, s = rem & 63;
        int c = (chalf << 5) + cl;
        int r = min(max(2 * lh - 1 + i, 0), 63);
        fl[cl * 257 + rem] = bsrc[(((size_t)((b << 6) + c)) << 12) + (r << 6) + s];
    }
    __syncthreads();
    ushort_t* Ah = Ahi + (size_t)b * A_BSTRIDE;
    ushort_t* Al = Alo + (size_t)b * A_BSTRIDE;
#pragma unroll
    for (int q = 0; q < 4; ++q) {
        int pair = t + (q << 8);         // 0..1023
        int lw = pair & 31, cl = pair >> 5;
        int c = (chalf << 5) + cl;
        float scale = invn[(b << 6) + c];
        const float* row = fl + cl * 257;
        __align__(16) ushort_t h[16];
        __align__(16) ushort_t lo[16];
#pragma unroll
        for (int i = 0; i < 4; ++i)
#pragma unroll
            for (int j = 0; j < 4; ++j) {
                int s = min(max(2 * lw - 1 + j, 0), 63);
                split_bf16(row[i * 64 + s] * scale, h[i * 4 + j], lo[i * 4 + j]);
            }
        int a = (lh * 64 + c) * 512 + lw * 8;
        *(uint4*)(Ah + a)       = *(uint4*)h;
        *(uint4*)(Ah + a + 256) = *(uint4*)(h + 8);
        *(uint4*)(Al + a)       = *(uint4*)lo;
        *(uint4*)(Al + a + 256) = *(uint4*)(lo + 8);
    }
}

// ---------------- kernel 3b: split B into fragment order ------------------
// block = (ph, b, chalf). ph==62 blocks also zero-fill pad rows 3969..4031.
__global__ __launch_bounds__(256) void splitB_kernel(const float* __restrict__ fsrc,
                                                     ushort_t* __restrict__ Bhi,
                                                     ushort_t* __restrict__ Blo) {
    __shared__ float fl[32 * 257];
    int ph = blockIdx.x, b = blockIdx.y, chalf = blockIdx.z;
    int t = threadIdx.x;
#pragma unroll
    for (int q = 0; q < 32; ++q) {
        int idx = t + (q << 8);
        int cl = idx >> 8, rem = idx & 255;
        int i = rem >> 6, s = rem & 63;
        int c = (chalf << 5) + cl;
        int r = min(max(ph - 1 + i, 0), 63);
        fl[cl * 257 + rem] = fsrc[(((size_t)((b << 6) + c)) << 12) + (r << 6) + s];
    }
    __syncthreads();
    ushort_t* Bh = Bhi + (size_t)b * B_BSTRIDE;
    ushort_t* Bl = Blo + (size_t)b * B_BSTRIDE;
#pragma unroll
    for (int q = 0; q < 8; ++q) {
        int pair = t + (q << 8);          // 0..2047
        int pw = pair & 63, cl = pair >> 6;
        if (pw < PHW) {
            int c = (chalf << 5) + cl;
            const float* row = fl + cl * 257;
            __align__(16) ushort_t h[16];
            __align__(16) ushort_t lo[16];
#pragma unroll
            for (int i = 0; i < 4; ++i)
#pragma unroll
                for (int j = 0; j < 4; ++j) {
                    int s = min(max(pw - 1 + j, 0), 63);
                    split_bf16(row[i * 64 + s], h[i * 4 + j], lo[i * 4 + j]);
                }
            int p = ph * PHW + pw;
            int a = frag_addr(p, c);
            *(uint4*)(Bh + a)       = *(uint4*)h;
            *(uint4*)(Bh + a + 256) = *(uint4*)(h + 8);
            *(uint4*)(Bl + a)       = *(uint4*)lo;
            *(uint4*)(Bl + a + 256) = *(uint4*)(lo + 8);
        }
    }
    if (ph == 62) {
        // zero pad rows: 3969..3999 (rtile 124, lanes 1..31) and 4000..4031 (rtile 125)
        uint4 z = {0, 0, 0, 0};
#pragma unroll
        for (int q = 0; q < 4; ++q) {
            int idx = t + (q << 8);      // 0..1023
            int r31 = idx & 31, cl = idx >> 5;
            int c = (chalf << 5) + cl;
            if (r31 < 31) {
                int a = (124 * 64 + c) * 512 + (1 + r31) * 8;
                *(uint4*)(Bh + a) = z; *(uint4*)(Bh + a + 256) = z;
                *(uint4*)(Bl + a) = z; *(uint4*)(Bl + a + 256) = z;
            }
            int a2 = (125 * 64 + c) * 512 + r31 * 8;
            *(uint4*)(Bh + a2) = z; *(uint4*)(Bh + a2 + 256) = z;
            *(uint4*)(Bl + a2) = z; *(uint4*)(Bl + a2 + 256) = z;
        }
    }
}

// ---------------- kernel 4: barrier-free LDS-free MFMA GEMM ---------------
// Rt[b][p][l] = sum_k B[p][k]*A[l][k], split-bf16 3-product.
// Wave tile 64l x 64p (2x2 of 32x32x16). Fragments loaded directly from
// fragment-ordered global arrays: 64 lanes x 16B = 1KB coalesced per load.
__global__ __launch_bounds__(256) void gemm_kernel(
    const ushort_t* __restrict__ Ahi, const ushort_t* __restrict__ Alo,
    const ushort_t* __restrict__ Bhi, const ushort_t* __restrict__ Blo,
    float* __restrict__ Rt) {
    int tid = threadIdx.x;
    int lane = tid & 63, w = tid >> 6;
    int bx = blockIdx.x;                 // 252 = 4 lgroups x 63 ptiles
    int b = blockIdx.y;
    int ltile = ((bx & 3) << 2) + w;     // 0..15
    int ptile = bx >> 2;                 // 0..62
    int l0 = ltile << 6, p0 = ptile << 6;

    size_t la = (size_t)b * A_BSTRIDE + ((l0 >> 5) * 64) * 512 + lane * 8;
    size_t lb = (size_t)b * B_BSTRIDE + ((p0 >> 5) * 64) * 512 + lane * 8;
    const ushort_t* ah0 = Ahi + la;  const ushort_t* ah1 = ah0 + 32768;
    const ushort_t* al0 = Alo + la;  const ushort_t* al1 = al0 + 32768;
    const ushort_t* bh0 = Bhi + lb;  const ushort_t* bh1 = bh0 + 32768;
    const ushort_t* bl0 = Blo + lb;  const ushort_t* bl1 = bl0 + 32768;

    floatx16 acc[2][2];
#pragma unroll
    for (int i = 0; i < 2; ++i)
#pragma unroll
        for (int j = 0; j < 2; ++j)
#pragma unroll
            for (int r = 0; r < 16; ++r) acc[i][j][r] = 0.f;

    short8 fa[8], fb[8];

#define LOADC(dst, kc)                                   \
    do {                                                 \
        int o = (kc) * 512;                              \
        dst[0] = *(const short8*)(ah0 + o);              \
        dst[1] = *(const short8*)(ah1 + o);              \
        dst[2] = *(const short8*)(al0 + o);              \
        dst[3] = *(const short8*)(al1 + o);              \
        dst[4] = *(const short8*)(bh0 + o);              \
        dst[5] = *(const short8*)(bh1 + o);              \
        dst[6] = *(const short8*)(bl0 + o);              \
        dst[7] = *(const short8*)(bl1 + o);              \
    } while (0)

#define COMP(f)                                                                                       \
    do {                                                                                              \
        _Pragma("unroll")                                                                             \
        for (int pt = 0; pt < 2; ++pt)                                                                \
            _Pragma("unroll")                                                                         \
            for (int lt = 0; lt < 2; ++lt) {                                                          \
                acc[pt][lt] = __builtin_amdgcn_mfma_f32_32x32x16_bf16(f[4 + pt], f[0 + lt], acc[pt][lt], 0, 0, 0); \
                acc[pt][lt] = __builtin_amdgcn_mfma_f32_32x32x16_bf16(f[4 + pt], f[2 + lt], acc[pt][lt], 0, 0, 0); \
                acc[pt][lt] = __builtin_amdgcn_mfma_f32_32x32x16_bf16(f[6 + pt], f[0 + lt], acc[pt][lt], 0, 0, 0); \
            }                                                                                         \
    } while (0)

    LOADC(fa, 0);
    for (int kc = 0; kc < 64; kc += 2) {
        LOADC(fb, kc + 1);
        COMP(fa);
        if (kc + 2 < 64) LOADC(fa, kc + 2);
        COMP(fb);
    }
#undef LOADC
#undef COMP

    int x = lane & 31, kg = lane >> 5;
#pragma unroll
    for (int pt = 0; pt < 2; ++pt)
#pragma unroll
        for (int lt = 0; lt < 2; ++lt)
#pragma unroll
            for (int r = 0; r < 16; ++r) {
                int p = p0 + (pt << 5) + (r & 3) + ((r >> 2) << 3) + (kg << 2);
                int l = l0 + (lt << 5) + x;
                if (p < NP) Rt[((size_t)b * NP + p) * NL + l] = acc[pt][lt][r];
            }
}

// ---------------- kernel 5: first diag3 pass ------------------------------
// D1[p][l] = Rt[p-1][l-1] + Rt[p][l] + Rt[p+1][l+1]   (flat-index zero pad)
__global__ __launch_bounds__(256) void diag1_kernel(const float* __restrict__ Rt,
                                                    float* __restrict__ D1) {
    int p = blockIdx.x, b = blockIdx.y;
    int t = threadIdx.x;
    const float* base = Rt + ((size_t)b * NP + p) * NL;
    int l4 = t << 2;
    float4 r = *(const float4*)(base + l4);
    if (p > 0) {
        const float* pm = base - NL;
        r.x += (l4 > 0) ? pm[l4 - 1] : 0.f;
        r.y += pm[l4];
        r.z += pm[l4 + 1];
        r.w += pm[l4 + 2];
    }
    if (p < NP - 1) {
        const float* pp = base + NL;
        r.x += pp[l4 + 1];
        r.y += pp[l4 + 2];
        r.z += pp[l4 + 3];
        r.w += (l4 + 4 < NL) ? pp[l4 + 4] : 0.f;
    }
    *(float4*)(D1 + ((size_t)b * NP + p) * NL + l4) = r;
}

// ---------------- kernel 6: closed-form diag2 + mask + softmax ------------
// F[l][p] = D1[p][l] + [ok-] D1[Pm][Lm(l)] + [ok+] D1[Pp][Lp(l)]
//  Pm = p-63 (ph>0) else 3905+pw;  excluded iff p==0
//  Pp = p+63 (ph<62) else pw+1;    excluded iff p==3968
//  Lm = l-32 (l>=32) else l+991 (l>0);  Lp = l+32 (l<992) else l-991 (l<1023)
__global__ __launch_bounds__(256) void epilogue_kernel(const float* __restrict__ D1,
                                                       const float* __restrict__ mmkA,
                                                       const float* __restrict__ mmpA,
                                                       float* __restrict__ out) {
    __shared__ float red[8];
    int p = blockIdx.x, b = blockIdx.y;
    int ph = p / PHW, pw = p - ph * PHW;
    int t = threadIdx.x;
    int lane = t & 63, w = t >> 6;
    int l0 = t << 2;

    const float* Db = D1 + (size_t)b * NP * NL;
    const float* rowc = Db + (size_t)p * NL;
    bool okm = (p != 0), okp = (p != 3968);
    int Pm = (ph > 0) ? p - 63 : 3905 + pw;
    int Pp = (ph < 62) ? p + 63 : pw + 1;
    const float* rowm = Db + (size_t)(okm ? Pm : 0) * NL;
    const float* rowp = Db + (size_t)(okp ? Pp : 0) * NL;

    float4 vc = *(const float4*)(rowc + l0);
    float4 vm = {0.f, 0.f, 0.f, 0.f}, vp = {0.f, 0.f, 0.f, 0.f};
    if (okm) {
        if (l0 >= 32) vm = *(const float4*)(rowm + l0 - 32);
        else {
            vm.x = (l0 == 0) ? 0.f : rowm[l0 + 991];
            vm.y = rowm[l0 + 992];
            vm.z = rowm[l0 + 993];
            vm.w = rowm[l0 + 994];
        }
    }
    if (okp) {
        if (l0 < 992) vp = *(const float4*)(rowp + l0 + 32);
        else {
            vp.x = rowp[l0 - 991];
            vp.y = rowp[l0 - 990];
            vp.z = rowp[l0 - 989];
            vp.w = (l0 + 3 == 1023) ? 0.f : rowp[l0 - 988];
        }
    }
    float mmpv = mmpA[b * NP + p];
    float4 km = *(const float4*)(mmkA + b * NL + l0);
    float lg[4];
    float fsum[4] = {vc.x + vm.x + vp.x, vc.y + vm.y + vp.y,
                     vc.z + vm.z + vp.z, vc.w + vm.w + vp.w};
    float kk[4] = {km.x, km.y, km.z, km.w};
#pragma unroll
    for (int i = 0; i < 4; ++i) {
        float mmv = (((kk[i] > mmpv) && (mmpv > 0.5f)) || (kk[i] == 1.0f)) ? 1.0f : 0.0f;
        lg[i] = fsum[i] * mmv * 10.0f;
    }
    // block-wide max
    float mx = fmaxf(fmaxf(lg[0], lg[1]), fmaxf(lg[2], lg[3]));
#pragma unroll
    for (int off = 32; off >= 1; off >>= 1) mx = fmaxf(mx, __shfl_xor(mx, off, 64));
    if (lane == 0) red[w] = mx;
    __syncthreads();
    mx = fmaxf(fmaxf(red[0], red[1]), fmaxf(red[2], red[3]));
    float e[4];
    float s = 0.f;
#pragma unroll
    for (int i = 0; i < 4; ++i) { e[i] = expf(lg[i] - mx); s += e[i]; }
#pragma unroll
    for (int off = 32; off >= 1; off >>= 1) s += __shfl_xor(s, off, 64);
    if (lane == 0) red[4 + w] = s;
    __syncthreads();
    float rinv = 1.0f / (red[4] + red[5] + red[6] + red[7]);
    float* op = out + ((size_t)b * NL + l0) * NP + p;
#pragma unroll
    for (int i = 0; i < 4; ++i) op[(size_t)i * NP] = e[i] * rinv;
}

extern "C" void kernel_launch(void* const* d_in, const int* in_sizes, int n_in,
                              void* d_out, int out_size, void* d_ws, size_t ws_size,
                              hipStream_t stream) {
    const float* f    = (const float*)d_in[0];
    const float* b    = (const float*)d_in[1];
    const float* mask = (const float*)d_in[2];
    float* out = (float*)d_out;

    // Rt lives in d_out (same size as output; consumed by diag1 before the
    // final epilogue overwrites d_out with softmax results).
    float* Rt = (float*)d_out;

    // ws: A'hi | A'lo | B'hi | B'lo  (82.8 MB), D1 overlays from ws start
    // after the GEMM; stats live past the A'/B' region.
    ushort_t* Ahi = (ushort_t*)d_ws;
    ushort_t* Alo = Ahi + (size_t)NB * A_BSTRIDE;
    ushort_t* Bhi = Alo + (size_t)NB * A_BSTRIDE;
    ushort_t* Blo = Bhi + (size_t)NB * B_BSTRIDE;
    float* D1 = (float*)d_ws;                  // overlay (used after GEMM)
    float* invn = (float*)(Blo + (size_t)NB * B_BSTRIDE);
    float* mmk = invn + 256;
    float* mmp = mmk + 4096;

    norm_kernel<<<dim3(256), dim3(256), 0, stream>>>(b, invn);
    stats_kernel<<<dim3(79), dim3(256), 0, stream>>>(mask, mmk, mmp);
    splitA_kernel<<<dim3(32, 4, 2), dim3(256), 0, stream>>>(b, invn, Ahi, Alo);
    splitB_kernel<<<dim3(63, 4, 2), dim3(256), 0, stream>>>(f, Bhi, Blo);
    gemm_kernel<<<dim3(252, 4), dim3(256), 0, stream>>>(Ahi, Alo, Bhi, Blo, Rt);
    diag1_kernel<<<dim3(3969, 4), dim3(256), 0, stream>>>(Rt, D1);
    epilogue_kernel<<<dim3(3969, 4), dim3(256), 0, stream>>>(D1, mmk, mmp, out);
}

// Round 6
// 302.574 us; speedup vs baseline: 1.3885x; 1.3885x over previous
//
#include <hip/hip_runtime.h>
#include <math.h>

#define NB 4
#define NC 64
#define NL 1024   // 32x32 kernel-patch grid
#define NP 3969   // 63x63 correlation positions
#define PHW 63

typedef unsigned short ushort_t;
typedef __attribute__((ext_vector_type(8))) short short8;
typedef __attribute__((ext_vector_type(16))) float floatx16;

// A' per b: 32 rtiles * 64 kchunks * 64 lanes * 8 = 2^20 ushorts
#define A_BSTRIDE 1048576
// B' per b: 126 rtiles (4032 rows, padded) * 64 * 64 * 8
#define B_BSTRIDE 4128768

// ---------------- kernel 1: per-(b,c) inverse L2 norm of b ----------------
__global__ __launch_bounds__(256) void norm_kernel(const float* __restrict__ bsrc,
                                                   float* __restrict__ invn) {
    int bc = blockIdx.x;  // 0..255
    const float* src = bsrc + (size_t)bc * 4096;
    float s = 0.f;
    for (int i = threadIdx.x; i < 4096; i += 256) { float v = src[i]; s += v * v; }
#pragma unroll
    for (int off = 32; off > 0; off >>= 1) s += __shfl_down(s, off, 64);
    __shared__ float part[4];
    if ((threadIdx.x & 63) == 0) part[threadIdx.x >> 6] = s;
    __syncthreads();
    if (threadIdx.x == 0) {
        float t = part[0] + part[1] + part[2] + part[3];
        invn[bc] = 1.0f / sqrtf(t + 1e-8f);
    }
}

// ---------------- kernel 2: patch means of (1-mask) -----------------------
__global__ __launch_bounds__(256) void stats_kernel(const float* __restrict__ mask,
                                                    float* __restrict__ mmk,
                                                    float* __restrict__ mmp) {
    int id = blockIdx.x * 256 + threadIdx.x;
    if (id < NB * NL) {
        int b = id >> 10, l = id & 1023;
        int lh = l >> 5, lw = l & 31;
        const float* m = mask + b * 4096;
        float s = 0.f;
#pragma unroll
        for (int i = 0; i < 4; ++i) {
            int r = min(max(2 * lh - 1 + i, 0), 63);
#pragma unroll
            for (int j = 0; j < 4; ++j) {
                int c = min(max(2 * lw - 1 + j, 0), 63);
                s += 1.0f - m[r * 64 + c];
            }
        }
        mmk[id] = s * (1.0f / 16.0f);
    } else {
        int id2 = id - NB * NL;
        if (id2 < NB * NP) {
            int b = id2 / NP, p = id2 - b * NP;
            int ph = p / PHW, pw = p - ph * PHW;
            const float* m = mask + b * 4096;
            float s = 0.f;
#pragma unroll
            for (int i = 0; i < 4; ++i) {
                int r = min(max(ph - 1 + i, 0), 63);
#pragma unroll
                for (int j = 0; j < 4; ++j) {
                    int c = min(max(pw - 1 + j, 0), 63);
                    s += 1.0f - m[r * 64 + c];
                }
            }
            mmp[id2] = s * (1.0f / 16.0f);
        }
    }
}

// ------------- split helper: fp32 -> bf16 hi + bf16 residual --------------
__device__ inline void split_bf16(float v, ushort_t& hv, ushort_t& lv) {
    unsigned u = __float_as_uint(v);
    unsigned rr = u + 0x7FFFu + ((u >> 16) & 1u);
    hv = (ushort_t)(rr >> 16);
    float fh = __uint_as_float(((unsigned)hv) << 16);
    float remv = v - fh;
    unsigned u2 = __float_as_uint(remv);
    unsigned rr2 = u2 + 0x7FFFu + ((u2 >> 16) & 1u);
    lv = (ushort_t)(rr2 >> 16);
}

// fragment-order address for (row, kchunk)
__device__ inline int frag_addr(int row, int kc) {
    return ((row >> 5) * 64 + kc) * 512 + (row & 31) * 8;
}

// ---------------- kernel 3a: split A into fragment order ------------------
__global__ __launch_bounds__(256) void splitA_kernel(const float* __restrict__ bsrc,
                                                     const float* __restrict__ invn,
                                                     ushort_t* __restrict__ Ahi,
                                                     ushort_t* __restrict__ Alo) {
    __shared__ float fl[32 * 257];
    int lh = blockIdx.x, b = blockIdx.y, chalf = blockIdx.z;
    int t = threadIdx.x;
#pragma unroll
    for (int q = 0; q < 32; ++q) {
        int idx = t + (q << 8);
        int cl = idx >> 8, rem = idx & 255;
        int i = rem >> 6, s = rem & 63;
        int c = (chalf << 5) + cl;
        int r = min(max(2 * lh - 1 + i, 0), 63);
        fl[cl * 257 + rem] = bsrc[(((size_t)((b << 6) + c)) << 12) + (r << 6) + s];
    }
    __syncthreads();
    ushort_t* Ah = Ahi + (size_t)b * A_BSTRIDE;
    ushort_t* Al = Alo + (size_t)b * A_BSTRIDE;
#pragma unroll
    for (int q = 0; q < 4; ++q) {
        int pair = t + (q << 8);         // 0..1023
        int lw = pair & 31, cl = pair >> 5;
        int c = (chalf << 5) + cl;
        float scale = invn[(b << 6) + c];
        const float* row = fl + cl * 257;
        __align__(16) ushort_t h[16];
        __align__(16) ushort_t lo[16];
#pragma unroll
        for (int i = 0; i < 4; ++i)
#pragma unroll
            for (int j = 0; j < 4; ++j) {
                int s = min(max(2 * lw - 1 + j, 0), 63);
                split_bf16(row[i * 64 + s] * scale, h[i * 4 + j], lo[i * 4 + j]);
            }
        int a = (lh * 64 + c) * 512 + lw * 8;
        *(uint4*)(Ah + a)       = *(uint4*)h;
        *(uint4*)(Ah + a + 256) = *(uint4*)(h + 8);
        *(uint4*)(Al + a)       = *(uint4*)lo;
        *(uint4*)(Al + a + 256) = *(uint4*)(lo + 8);
    }
}

// ---------------- kernel 3b: split B into fragment order ------------------
__global__ __launch_bounds__(256) void splitB_kernel(const float* __restrict__ fsrc,
                                                     ushort_t* __restrict__ Bhi,
                                                     ushort_t* __restrict__ Blo) {
    __shared__ float fl[32 * 257];
    int ph = blockIdx.x, b = blockIdx.y, chalf = blockIdx.z;
    int t = threadIdx.x;
#pragma unroll
    for (int q = 0; q < 32; ++q) {
        int idx = t + (q << 8);
        int cl = idx >> 8, rem = idx & 255;
        int i = rem >> 6, s = rem & 63;
        int c = (chalf << 5) + cl;
        int r = min(max(ph - 1 + i, 0), 63);
        fl[cl * 257 + rem] = fsrc[(((size_t)((b << 6) + c)) << 12) + (r << 6) + s];
    }
    __syncthreads();
    ushort_t* Bh = Bhi + (size_t)b * B_BSTRIDE;
    ushort_t* Bl = Blo + (size_t)b * B_BSTRIDE;
#pragma unroll
    for (int q = 0; q < 8; ++q) {
        int pair = t + (q << 8);          // 0..2047
        int pw = pair & 63, cl = pair >> 6;
        if (pw < PHW) {
            int c = (chalf << 5) + cl;
            const float* row = fl + cl * 257;
            __align__(16) ushort_t h[16];
            __align__(16) ushort_t lo[16];
#pragma unroll
            for (int i = 0; i < 4; ++i)
#pragma unroll
                for (int j = 0; j < 4; ++j) {
                    int s = min(max(pw - 1 + j, 0), 63);
                    split_bf16(row[i * 64 + s], h[i * 4 + j], lo[i * 4 + j]);
                }
            int p = ph * PHW + pw;
            int a = frag_addr(p, c);
            *(uint4*)(Bh + a)       = *(uint4*)h;
            *(uint4*)(Bh + a + 256) = *(uint4*)(h + 8);
            *(uint4*)(Bl + a)       = *(uint4*)lo;
            *(uint4*)(Bl + a + 256) = *(uint4*)(lo + 8);
        }
    }
    if (ph == 62) {
        uint4 z = {0, 0, 0, 0};
#pragma unroll
        for (int q = 0; q < 4; ++q) {
            int idx = t + (q << 8);      // 0..1023
            int r31 = idx & 31, cl = idx >> 5;
            int c = (chalf << 5) + cl;
            if (r31 < 31) {
                int a = (124 * 64 + c) * 512 + (1 + r31) * 8;
                *(uint4*)(Bh + a) = z; *(uint4*)(Bh + a + 256) = z;
                *(uint4*)(Bl + a) = z; *(uint4*)(Bl + a + 256) = z;
            }
            int a2 = (125 * 64 + c) * 512 + r31 * 8;
            *(uint4*)(Bh + a2) = z; *(uint4*)(Bh + a2 + 256) = z;
            *(uint4*)(Bl + a2) = z; *(uint4*)(Bl + a2 + 256) = z;
        }
    }
}

// ---------------- kernel 4: barrier-free LDS-free MFMA GEMM ---------------
__global__ __launch_bounds__(256) void gemm_kernel(
    const ushort_t* __restrict__ Ahi, const ushort_t* __restrict__ Alo,
    const ushort_t* __restrict__ Bhi, const ushort_t* __restrict__ Blo,
    float* __restrict__ Rt) {
    int tid = threadIdx.x;
    int lane = tid & 63, w = tid >> 6;
    int bx = blockIdx.x;                 // 252 = 4 lgroups x 63 ptiles
    int b = blockIdx.y;
    int ltile = ((bx & 3) << 2) + w;     // 0..15
    int ptile = bx >> 2;                 // 0..62
    int l0 = ltile << 6, p0 = ptile << 6;

    size_t la = (size_t)b * A_BSTRIDE + ((l0 >> 5) * 64) * 512 + lane * 8;
    size_t lb = (size_t)b * B_BSTRIDE + ((p0 >> 5) * 64) * 512 + lane * 8;
    const ushort_t* ah0 = Ahi + la;  const ushort_t* ah1 = ah0 + 32768;
    const ushort_t* al0 = Alo + la;  const ushort_t* al1 = al0 + 32768;
    const ushort_t* bh0 = Bhi + lb;  const ushort_t* bh1 = bh0 + 32768;
    const ushort_t* bl0 = Blo + lb;  const ushort_t* bl1 = bl0 + 32768;

    floatx16 acc[2][2];
#pragma unroll
    for (int i = 0; i < 2; ++i)
#pragma unroll
        for (int j = 0; j < 2; ++j)
#pragma unroll
            for (int r = 0; r < 16; ++r) acc[i][j][r] = 0.f;

    short8 fa[8], fb[8];

#define LOADC(dst, kc)                                   \
    do {                                                 \
        int o = (kc) * 512;                              \
        dst[0] = *(const short8*)(ah0 + o);              \
        dst[1] = *(const short8*)(ah1 + o);              \
        dst[2] = *(const short8*)(al0 + o);              \
        dst[3] = *(const short8*)(al1 + o);              \
        dst[4] = *(const short8*)(bh0 + o);              \
        dst[5] = *(const short8*)(bh1 + o);              \
        dst[6] = *(const short8*)(bl0 + o);              \
        dst[7] = *(const short8*)(bl1 + o);              \
    } while (0)

#define COMP(f)                                                                                       \
    do {                                                                                              \
        _Pragma("unroll")                                                                             \
        for (int pt = 0; pt < 2; ++pt)                                                                \
            _Pragma("unroll")                                                                         \
            for (int lt = 0; lt < 2; ++lt) {                                                          \
                acc[pt][lt] = __builtin_amdgcn_mfma_f32_32x32x16_bf16(f[4 + pt], f[0 + lt], acc[pt][lt], 0, 0, 0); \
                acc[pt][lt] = __builtin_amdgcn_mfma_f32_32x32x16_bf16(f[4 + pt], f[2 + lt], acc[pt][lt], 0, 0, 0); \
                acc[pt][lt] = __builtin_amdgcn_mfma_f32_32x32x16_bf16(f[6 + pt], f[0 + lt], acc[pt][lt], 0, 0, 0); \
            }                                                                                         \
    } while (0)

    LOADC(fa, 0);
    for (int kc = 0; kc < 64; kc += 2) {
        LOADC(fb, kc + 1);
        COMP(fa);
        if (kc + 2 < 64) LOADC(fa, kc + 2);
        COMP(fb);
    }
#undef LOADC
#undef COMP

    int x = lane & 31, kg = lane >> 5;
#pragma unroll
    for (int pt = 0; pt < 2; ++pt)
#pragma unroll
        for (int lt = 0; lt < 2; ++lt)
#pragma unroll
            for (int r = 0; r < 16; ++r) {
                int p = p0 + (pt << 5) + (r & 3) + ((r >> 2) << 3) + (kg << 2);
                int l = l0 + (lt << 5) + x;
                if (p < NP) Rt[((size_t)b * NP + p) * NL + l] = acc[pt][lt][r];
            }
}

// ---------------- kernel 5: first diag3 pass ------------------------------
// D1[p][l] = Rt[p-1][l-1] + Rt[p][l] + Rt[p+1][l+1]   (flat-index zero pad)
__global__ __launch_bounds__(256) void diag1_kernel(const float* __restrict__ Rt,
                                                    float* __restrict__ D1) {
    int p = blockIdx.x, b = blockIdx.y;
    int t = threadIdx.x;
    const float* base = Rt + ((size_t)b * NP + p) * NL;
    int l4 = t << 2;
    float4 r = *(const float4*)(base + l4);
    if (p > 0) {
        const float* pm = base - NL;
        r.x += (l4 > 0) ? pm[l4 - 1] : 0.f;
        r.y += pm[l4];
        r.z += pm[l4 + 1];
        r.w += pm[l4 + 2];
    }
    if (p < NP - 1) {
        const float* pp = base + NL;
        r.x += pp[l4 + 1];
        r.y += pp[l4 + 2];
        r.z += pp[l4 + 3];
        r.w += (l4 + 4 < NL) ? pp[l4 + 4] : 0.f;
    }
    *(float4*)(D1 + ((size_t)b * NP + p) * NL + l4) = r;
}

// ---------------- kernel 6: diag2 + mask + softmax, row output ------------
// E[p][l] = softmax_l-normalized value, written CONTIGUOUSLY per p-row.
__global__ __launch_bounds__(256) void softmax_rows_kernel(const float* __restrict__ D1,
                                                           const float* __restrict__ mmkA,
                                                           const float* __restrict__ mmpA,
                                                           float* __restrict__ E) {
    __shared__ float red[8];
    int p = blockIdx.x, b = blockIdx.y;
    int ph = p / PHW, pw = p - ph * PHW;
    int t = threadIdx.x;
    int lane = t & 63, w = t >> 6;
    int l0 = t << 2;

    const float* Db = D1 + (size_t)b * NP * NL;
    const float* rowc = Db + (size_t)p * NL;
    bool okm = (p != 0), okp = (p != 3968);
    int Pm = (ph > 0) ? p - 63 : 3905 + pw;
    int Pp = (ph < 62) ? p + 63 : pw + 1;
    const float* rowm = Db + (size_t)(okm ? Pm : 0) * NL;
    const float* rowp = Db + (size_t)(okp ? Pp : 0) * NL;

    float4 vc = *(const float4*)(rowc + l0);
    float4 vm = {0.f, 0.f, 0.f, 0.f}, vp = {0.f, 0.f, 0.f, 0.f};
    if (okm) {
        if (l0 >= 32) vm = *(const float4*)(rowm + l0 - 32);
        else {
            vm.x = (l0 == 0) ? 0.f : rowm[l0 + 991];
            vm.y = rowm[l0 + 992];
            vm.z = rowm[l0 + 993];
            vm.w = rowm[l0 + 994];
        }
    }
    if (okp) {
        if (l0 < 992) vp = *(const float4*)(rowp + l0 + 32);
        else {
            vp.x = rowp[l0 - 991];
            vp.y = rowp[l0 - 990];
            vp.z = rowp[l0 - 989];
            vp.w = (l0 + 3 == 1023) ? 0.f : rowp[l0 - 988];
        }
    }
    float mmpv = mmpA[b * NP + p];
    float4 km = *(const float4*)(mmkA + b * NL + l0);
    float lg[4];
    float fsum[4] = {vc.x + vm.x + vp.x, vc.y + vm.y + vp.y,
                     vc.z + vm.z + vp.z, vc.w + vm.w + vp.w};
    float kk[4] = {km.x, km.y, km.z, km.w};
#pragma unroll
    for (int i = 0; i < 4; ++i) {
        float mmv = (((kk[i] > mmpv) && (mmpv > 0.5f)) || (kk[i] == 1.0f)) ? 1.0f : 0.0f;
        lg[i] = fsum[i] * mmv * 10.0f;
    }
    float mx = fmaxf(fmaxf(lg[0], lg[1]), fmaxf(lg[2], lg[3]));
#pragma unroll
    for (int off = 32; off >= 1; off >>= 1) mx = fmaxf(mx, __shfl_xor(mx, off, 64));
    if (lane == 0) red[w] = mx;
    __syncthreads();
    mx = fmaxf(fmaxf(red[0], red[1]), fmaxf(red[2], red[3]));
    float e[4];
    float s = 0.f;
#pragma unroll
    for (int i = 0; i < 4; ++i) { e[i] = expf(lg[i] - mx); s += e[i]; }
#pragma unroll
    for (int off = 32; off >= 1; off >>= 1) s += __shfl_xor(s, off, 64);
    if (lane == 0) red[4 + w] = s;
    __syncthreads();
    float rinv = 1.0f / (red[4] + red[5] + red[6] + red[7]);
    float4 ev = {e[0] * rinv, e[1] * rinv, e[2] * rinv, e[3] * rinv};
    *(float4*)(E + (((size_t)b * NP + p) << 10) + l0) = ev;
}

// ---------------- kernel 7: tiled transpose E[p][l] -> out[l][p] ----------
__global__ __launch_bounds__(256) void transpose_kernel(const float* __restrict__ E,
                                                        float* __restrict__ out) {
    __shared__ float tile[63 * 65];
    int pt = blockIdx.x;       // 0..62 : p0 = pt*63
    int lt = blockIdx.y;       // 0..15 : l0 = lt*64
    int b  = blockIdx.z;
    int t = threadIdx.x;
    int p0 = pt * 63, l0 = lt << 6;
    const float* Eb = E + ((size_t)b * NP << 10);
    {
        int j = t & 63, i4 = t >> 6;
#pragma unroll
        for (int k = 0; k < 16; ++k) {
            int i = (k << 2) + i4;
            if (i < 63) tile[i * 65 + j] = Eb[((size_t)(p0 + i) << 10) + l0 + j];
        }
    }
    __syncthreads();
    {
        int ii = t & 63, jj4 = t >> 6;
        if (ii < 63) {
#pragma unroll
            for (int k = 0; k < 16; ++k) {
                int jj = (k << 2) + jj4;
                out[((size_t)b * NL + l0 + jj) * NP + p0 + ii] = tile[ii * 65 + jj];
            }
        }
    }
}

extern "C" void kernel_launch(void* const* d_in, const int* in_sizes, int n_in,
                              void* d_out, int out_size, void* d_ws, size_t ws_size,
                              hipStream_t stream) {
    const float* f    = (const float*)d_in[0];
    const float* b    = (const float*)d_in[1];
    const float* mask = (const float*)d_in[2];
    float* out = (float*)d_out;

    // Rt lives in d_out (consumed by diag1 before transpose overwrites out).
    float* Rt = (float*)d_out;

    // ws layout (floats): D1 [0 .. 16257024) ; E [16257024 .. 32514048) ;
    // stats after. A'/B' (82.8 MB) overlap D1+E but are dead post-GEMM.
    float* wsf = (float*)d_ws;
    float* D1 = wsf;
    float* E  = wsf + 16257024;
    ushort_t* Ahi = (ushort_t*)d_ws;
    ushort_t* Alo = Ahi + (size_t)NB * A_BSTRIDE;
    ushort_t* Bhi = Alo + (size_t)NB * A_BSTRIDE;
    ushort_t* Blo = Bhi + (size_t)NB * B_BSTRIDE;
    float* invn = wsf + 32514048;
    float* mmk = invn + 256;
    float* mmp = mmk + 4096;

    norm_kernel<<<dim3(256), dim3(256), 0, stream>>>(b, invn);
    stats_kernel<<<dim3(79), dim3(256), 0, stream>>>(mask, mmk, mmp);
    splitA_kernel<<<dim3(32, 4, 2), dim3(256), 0, stream>>>(b, invn, Ahi, Alo);
    splitB_kernel<<<dim3(63, 4, 2), dim3(256), 0, stream>>>(f, Bhi, Blo);
    gemm_kernel<<<dim3(252, 4), dim3(256), 0, stream>>>(Ahi, Alo, Bhi, Blo, Rt);
    diag1_kernel<<<dim3(3969, 4), dim3(256), 0, stream>>>(Rt, D1);
    softmax_rows_kernel<<<dim3(3969, 4), dim3(256), 0, stream>>>(D1, mmk, mmp, E);
    transpose_kernel<<<dim3(63, 16, 4), dim3(256), 0, stream>>>(E, out);
}

// Round 7
// 297.895 us; speedup vs baseline: 1.4103x; 1.0157x over previous
//
#include <hip/hip_runtime.h>
#include <math.h>

#define NB 4
#define NC 64
#define NL 1024   // 32x32 kernel-patch grid
#define NP 3969   // 63x63 correlation positions
#define PHW 63

typedef unsigned short ushort_t;
typedef __attribute__((ext_vector_type(8))) short short8;
typedef __attribute__((ext_vector_type(16))) float floatx16;

// A' per b: 32 rtiles * 64 kchunks * 64 lanes * 8 = 2^20 ushorts
#define A_BSTRIDE 1048576
// B' per b: 126 rtiles (4032 rows, padded) * 64 * 64 * 8
#define B_BSTRIDE 4128768

// ---------------- kernel 1: per-(b,c) inverse L2 norm of b ----------------
__global__ __launch_bounds__(256) void norm_kernel(const float* __restrict__ bsrc,
                                                   float* __restrict__ invn) {
    int bc = blockIdx.x;  // 0..255
    const float* src = bsrc + (size_t)bc * 4096;
    float s = 0.f;
    for (int i = threadIdx.x; i < 4096; i += 256) { float v = src[i]; s += v * v; }
#pragma unroll
    for (int off = 32; off > 0; off >>= 1) s += __shfl_down(s, off, 64);
    __shared__ float part[4];
    if ((threadIdx.x & 63) == 0) part[threadIdx.x >> 6] = s;
    __syncthreads();
    if (threadIdx.x == 0) {
        float t = part[0] + part[1] + part[2] + part[3];
        invn[bc] = 1.0f / sqrtf(t + 1e-8f);
    }
}

// ---------------- kernel 2: patch means of (1-mask) -----------------------
__global__ __launch_bounds__(256) void stats_kernel(const float* __restrict__ mask,
                                                    float* __restrict__ mmk,
                                                    float* __restrict__ mmp) {
    int id = blockIdx.x * 256 + threadIdx.x;
    if (id < NB * NL) {
        int b = id >> 10, l = id & 1023;
        int lh = l >> 5, lw = l & 31;
        const float* m = mask + b * 4096;
        float s = 0.f;
#pragma unroll
        for (int i = 0; i < 4; ++i) {
            int r = min(max(2 * lh - 1 + i, 0), 63);
#pragma unroll
            for (int j = 0; j < 4; ++j) {
                int c = min(max(2 * lw - 1 + j, 0), 63);
                s += 1.0f - m[r * 64 + c];
            }
        }
        mmk[id] = s * (1.0f / 16.0f);
    } else {
        int id2 = id - NB * NL;
        if (id2 < NB * NP) {
            int b = id2 / NP, p = id2 - b * NP;
            int ph = p / PHW, pw = p - ph * PHW;
            const float* m = mask + b * 4096;
            float s = 0.f;
#pragma unroll
            for (int i = 0; i < 4; ++i) {
                int r = min(max(ph - 1 + i, 0), 63);
#pragma unroll
                for (int j = 0; j < 4; ++j) {
                    int c = min(max(pw - 1 + j, 0), 63);
                    s += 1.0f - m[r * 64 + c];
                }
            }
            mmp[id2] = s * (1.0f / 16.0f);
        }
    }
}

// ------------- split helper: fp32 -> bf16 hi + bf16 residual --------------
__device__ inline void split_bf16(float v, ushort_t& hv, ushort_t& lv) {
    unsigned u = __float_as_uint(v);
    unsigned rr = u + 0x7FFFu + ((u >> 16) & 1u);
    hv = (ushort_t)(rr >> 16);
    float fh = __uint_as_float(((unsigned)hv) << 16);
    float remv = v - fh;
    unsigned u2 = __float_as_uint(remv);
    unsigned rr2 = u2 + 0x7FFFu + ((u2 >> 16) & 1u);
    lv = (ushort_t)(rr2 >> 16);
}

// fragment-order address for (row, kchunk)
__device__ inline int frag_addr(int row, int kc) {
    return ((row >> 5) * 64 + kc) * 512 + (row & 31) * 8;
}

// ---------------- kernel 3a: split A into fragment order ------------------
__global__ __launch_bounds__(256) void splitA_kernel(const float* __restrict__ bsrc,
                                                     const float* __restrict__ invn,
                                                     ushort_t* __restrict__ Ahi,
                                                     ushort_t* __restrict__ Alo) {
    __shared__ float fl[32 * 257];
    int lh = blockIdx.x, b = blockIdx.y, chalf = blockIdx.z;
    int t = threadIdx.x;
#pragma unroll
    for (int q = 0; q < 32; ++q) {
        int idx = t + (q << 8);
        int cl = idx >> 8, rem = idx & 255;
        int i = rem >> 6, s = rem & 63;
        int c = (chalf << 5) + cl;
        int r = min(max(2 * lh - 1 + i, 0), 63);
        fl[cl * 257 + rem] = bsrc[(((size_t)((b << 6) + c)) << 12) + (r << 6) + s];
    }
    __syncthreads();
    ushort_t* Ah = Ahi + (size_t)b * A_BSTRIDE;
    ushort_t* Al = Alo + (size_t)b * A_BSTRIDE;
#pragma unroll
    for (int q = 0; q < 4; ++q) {
        int pair = t + (q << 8);         // 0..1023
        int lw = pair & 31, cl = pair >> 5;
        int c = (chalf << 5) + cl;
        float scale = invn[(b << 6) + c];
        const float* row = fl + cl * 257;
        __align__(16) ushort_t h[16];
        __align__(16) ushort_t lo[16];
#pragma unroll
        for (int i = 0; i < 4; ++i)
#pragma unroll
            for (int j = 0; j < 4; ++j) {
                int s = min(max(2 * lw - 1 + j, 0), 63);
                split_bf16(row[i * 64 + s] * scale, h[i * 4 + j], lo[i * 4 + j]);
            }
        int a = (lh * 64 + c) * 512 + lw * 8;
        *(uint4*)(Ah + a)       = *(uint4*)h;
        *(uint4*)(Ah + a + 256) = *(uint4*)(h + 8);
        *(uint4*)(Al + a)       = *(uint4*)lo;
        *(uint4*)(Al + a + 256) = *(uint4*)(lo + 8);
    }
}

// ---------------- kernel 3b: split B into fragment order ------------------
__global__ __launch_bounds__(256) void splitB_kernel(const float* __restrict__ fsrc,
                                                     ushort_t* __restrict__ Bhi,
                                                     ushort_t* __restrict__ Blo) {
    __shared__ float fl[32 * 257];
    int ph = blockIdx.x, b = blockIdx.y, chalf = blockIdx.z;
    int t = threadIdx.x;
#pragma unroll
    for (int q = 0; q < 32; ++q) {
        int idx = t + (q << 8);
        int cl = idx >> 8, rem = idx & 255;
        int i = rem >> 6, s = rem & 63;
        int c = (chalf << 5) + cl;
        int r = min(max(ph - 1 + i, 0), 63);
        fl[cl * 257 + rem] = fsrc[(((size_t)((b << 6) + c)) << 12) + (r << 6) + s];
    }
    __syncthreads();
    ushort_t* Bh = Bhi + (size_t)b * B_BSTRIDE;
    ushort_t* Bl = Blo + (size_t)b * B_BSTRIDE;
#pragma unroll
    for (int q = 0; q < 8; ++q) {
        int pair = t + (q << 8);          // 0..2047
        int pw = pair & 63, cl = pair >> 6;
        if (pw < PHW) {
            int c = (chalf << 5) + cl;
            const float* row = fl + cl * 257;
            __align__(16) ushort_t h[16];
            __align__(16) ushort_t lo[16];
#pragma unroll
            for (int i = 0; i < 4; ++i)
#pragma unroll
                for (int j = 0; j < 4; ++j) {
                    int s = min(max(pw - 1 + j, 0), 63);
                    split_bf16(row[i * 64 + s], h[i * 4 + j], lo[i * 4 + j]);
                }
            int p = ph * PHW + pw;
            int a = frag_addr(p, c);
            *(uint4*)(Bh + a)       = *(uint4*)h;
            *(uint4*)(Bh + a + 256) = *(uint4*)(h + 8);
            *(uint4*)(Bl + a)       = *(uint4*)lo;
            *(uint4*)(Bl + a + 256) = *(uint4*)(lo + 8);
        }
    }
    if (ph == 62) {
        uint4 z = {0, 0, 0, 0};
#pragma unroll
        for (int q = 0; q < 4; ++q) {
            int idx = t + (q << 8);      // 0..1023
            int r31 = idx & 31, cl = idx >> 5;
            int c = (chalf << 5) + cl;
            if (r31 < 31) {
                int a = (124 * 64 + c) * 512 + (1 + r31) * 8;
                *(uint4*)(Bh + a) = z; *(uint4*)(Bh + a + 256) = z;
                *(uint4*)(Bl + a) = z; *(uint4*)(Bl + a + 256) = z;
            }
            int a2 = (125 * 64 + c) * 512 + r31 * 8;
            *(uint4*)(Bh + a2) = z; *(uint4*)(Bh + a2 + 256) = z;
            *(uint4*)(Bl + a2) = z; *(uint4*)(Bl + a2 + 256) = z;
        }
    }
}

// ---------------- kernel 4: barrier-free MFMA GEMM, depth-4 prefetch ------
__global__ __launch_bounds__(256, 2) void gemm_kernel(
    const ushort_t* __restrict__ Ahi, const ushort_t* __restrict__ Alo,
    const ushort_t* __restrict__ Bhi, const ushort_t* __restrict__ Blo,
    float* __restrict__ Rt) {
    int tid = threadIdx.x;
    int lane = tid & 63, w = tid >> 6;
    int bx = blockIdx.x;                 // 252 = 4 lgroups x 63 ptiles
    int b = blockIdx.y;
    int ltile = ((bx & 3) << 2) + w;     // 0..15
    int ptile = bx >> 2;                 // 0..62
    int l0 = ltile << 6, p0 = ptile << 6;

    size_t la = (size_t)b * A_BSTRIDE + ((l0 >> 5) * 64) * 512 + lane * 8;
    size_t lb = (size_t)b * B_BSTRIDE + ((p0 >> 5) * 64) * 512 + lane * 8;
    const ushort_t* ah0 = Ahi + la;  const ushort_t* ah1 = ah0 + 32768;
    const ushort_t* al0 = Alo + la;  const ushort_t* al1 = al0 + 32768;
    const ushort_t* bh0 = Bhi + lb;  const ushort_t* bh1 = bh0 + 32768;
    const ushort_t* bl0 = Blo + lb;  const ushort_t* bl1 = bl0 + 32768;

    floatx16 acc[2][2];
#pragma unroll
    for (int i = 0; i < 2; ++i)
#pragma unroll
        for (int j = 0; j < 2; ++j)
#pragma unroll
            for (int r = 0; r < 16; ++r) acc[i][j][r] = 0.f;

    short8 f[4][8];

#define LOADC(dst, kc)                                   \
    do {                                                 \
        int o = (kc) * 512;                              \
        dst[0] = *(const short8*)(ah0 + o);              \
        dst[1] = *(const short8*)(ah1 + o);              \
        dst[2] = *(const short8*)(al0 + o);              \
        dst[3] = *(const short8*)(al1 + o);              \
        dst[4] = *(const short8*)(bh0 + o);              \
        dst[5] = *(const short8*)(bh1 + o);              \
        dst[6] = *(const short8*)(bl0 + o);              \
        dst[7] = *(const short8*)(bl1 + o);              \
    } while (0)

#define COMP(g)                                                                                       \
    do {                                                                                              \
        _Pragma("unroll")                                                                             \
        for (int pt = 0; pt < 2; ++pt)                                                                \
            _Pragma("unroll")                                                                         \
            for (int lt = 0; lt < 2; ++lt) {                                                          \
                acc[pt][lt] = __builtin_amdgcn_mfma_f32_32x32x16_bf16(g[4 + pt], g[0 + lt], acc[pt][lt], 0, 0, 0); \
                acc[pt][lt] = __builtin_amdgcn_mfma_f32_32x32x16_bf16(g[4 + pt], g[2 + lt], acc[pt][lt], 0, 0, 0); \
                acc[pt][lt] = __builtin_amdgcn_mfma_f32_32x32x16_bf16(g[6 + pt], g[0 + lt], acc[pt][lt], 0, 0, 0); \
            }                                                                                         \
    } while (0)

    LOADC(f[0], 0);
    LOADC(f[1], 1);
    LOADC(f[2], 2);
    for (int kc = 0; kc < 64; kc += 4) {
        LOADC(f[3], min(kc + 3, 63));
        COMP(f[0]);
        LOADC(f[0], min(kc + 4, 63));
        COMP(f[1]);
        LOADC(f[1], min(kc + 5, 63));
        COMP(f[2]);
        LOADC(f[2], min(kc + 6, 63));
        COMP(f[3]);
    }
#undef LOADC
#undef COMP

    int x = lane & 31, kg = lane >> 5;
#pragma unroll
    for (int pt = 0; pt < 2; ++pt)
#pragma unroll
        for (int lt = 0; lt < 2; ++lt)
#pragma unroll
            for (int r = 0; r < 16; ++r) {
                int p = p0 + (pt << 5) + (r & 3) + ((r >> 2) << 3) + (kg << 2);
                int l = l0 + (lt << 5) + x;
                if (p < NP) Rt[((size_t)b * NP + p) * NL + l] = acc[pt][lt][r];
            }
}

// ------- kernel 5: fused diag1 + diag2 + mask + softmax, row output -------
// Builds D1 rows {p, Pm, Pp} from Rt in LDS (exact diag1 zero-pad math),
// then F[l] = ld0[l] + [okm] ld1[Lm(l)] + [okp] ld2[Lp(l)], mask, softmax,
// and writes normalized row E[p][l] contiguously.
__global__ __launch_bounds__(256) void softmax_fused_kernel(const float* __restrict__ Rt,
                                                            const float* __restrict__ mmkA,
                                                            const float* __restrict__ mmpA,
                                                            float* __restrict__ E) {
    __shared__ float ld0[1024], ld1[1024], ld2[1024];
    __shared__ float red[8];
    int p = blockIdx.x, b = blockIdx.y;
    int ph = p / PHW, pw = p - ph * PHW;
    int t = threadIdx.x;
    int lane = t & 63, w = t >> 6;
    int l0 = t << 2;

    bool okm = (p != 0), okp = (p != 3968);
    int Pm = (ph > 0) ? p - 63 : 3905 + pw;
    int Pp = (ph < 62) ? p + 63 : pw + 1;

    const float* Rb = Rt + (size_t)b * NP * NL;
    // build D1 row q into dst (same math as the verified diag1 kernel)
#define BUILD(dst, q)                                                   \
    do {                                                                \
        const float* base = Rb + (size_t)(q) * NL;                      \
        float4 r = *(const float4*)(base + l0);                         \
        if ((q) > 0) {                                                  \
            const float* pm = base - NL;                                \
            r.x += (l0 > 0) ? pm[l0 - 1] : 0.f;                         \
            r.y += pm[l0];  r.z += pm[l0 + 1];  r.w += pm[l0 + 2];      \
        }                                                               \
        if ((q) < NP - 1) {                                             \
            const float* pp = base + NL;                                \
            r.x += pp[l0 + 1];  r.y += pp[l0 + 2];  r.z += pp[l0 + 3];  \
            r.w += (l0 + 4 < NL) ? pp[l0 + 4] : 0.f;                    \
        }                                                               \
        *(float4*)(dst + l0) = r;                                       \
    } while (0)

    BUILD(ld0, p);
    if (okm) BUILD(ld1, Pm);
    if (okp) BUILD(ld2, Pp);
#undef BUILD
    __syncthreads();

    float4 vc = *(const float4*)(ld0 + l0);
    float4 vm = {0.f, 0.f, 0.f, 0.f}, vp = {0.f, 0.f, 0.f, 0.f};
    if (okm) {
        if (l0 >= 32) vm = *(const float4*)(ld1 + l0 - 32);
        else {
            vm.x = (l0 == 0) ? 0.f : ld1[l0 + 991];
            vm.y = ld1[l0 + 992];
            vm.z = ld1[l0 + 993];
            vm.w = ld1[l0 + 994];
        }
    }
    if (okp) {
        if (l0 < 992) vp = *(const float4*)(ld2 + l0 + 32);
        else {
            vp.x = ld2[l0 - 991];
            vp.y = ld2[l0 - 990];
            vp.z = ld2[l0 - 989];
            vp.w = (l0 + 3 == 1023) ? 0.f : ld2[l0 - 988];
        }
    }
    float mmpv = mmpA[b * NP + p];
    float4 km = *(const float4*)(mmkA + b * NL + l0);
    float lg[4];
    float fsum[4] = {vc.x + vm.x + vp.x, vc.y + vm.y + vp.y,
                     vc.z + vm.z + vp.z, vc.w + vm.w + vp.w};
    float kk[4] = {km.x, km.y, km.z, km.w};
#pragma unroll
    for (int i = 0; i < 4; ++i) {
        float mmv = (((kk[i] > mmpv) && (mmpv > 0.5f)) || (kk[i] == 1.0f)) ? 1.0f : 0.0f;
        lg[i] = fsum[i] * mmv * 10.0f;
    }
    float mx = fmaxf(fmaxf(lg[0], lg[1]), fmaxf(lg[2], lg[3]));
#pragma unroll
    for (int off = 32; off >= 1; off >>= 1) mx = fmaxf(mx, __shfl_xor(mx, off, 64));
    if (lane == 0) red[w] = mx;
    __syncthreads();
    mx = fmaxf(fmaxf(red[0], red[1]), fmaxf(red[2], red[3]));
    float e[4];
    float s = 0.f;
#pragma unroll
    for (int i = 0; i < 4; ++i) { e[i] = expf(lg[i] - mx); s += e[i]; }
#pragma unroll
    for (int off = 32; off >= 1; off >>= 1) s += __shfl_xor(s, off, 64);
    if (lane == 0) red[4 + w] = s;
    __syncthreads();
    float rinv = 1.0f / (red[4] + red[5] + red[6] + red[7]);
    float4 ev = {e[0] * rinv, e[1] * rinv, e[2] * rinv, e[3] * rinv};
    *(float4*)(E + (((size_t)b * NP + p) << 10) + l0) = ev;
}

// ---------------- kernel 6: tiled transpose E[p][l] -> out[l][p] ----------
__global__ __launch_bounds__(256) void transpose_kernel(const float* __restrict__ E,
                                                        float* __restrict__ out) {
    __shared__ float tile[63 * 65];
    int pt = blockIdx.x;       // 0..62 : p0 = pt*63
    int lt = blockIdx.y;       // 0..15 : l0 = lt*64
    int b  = blockIdx.z;
    int t = threadIdx.x;
    int p0 = pt * 63, l0 = lt << 6;
    const float* Eb = E + ((size_t)b * NP << 10);
    {
        int j = t & 63, i4 = t >> 6;
#pragma unroll
        for (int k = 0; k < 16; ++k) {
            int i = (k << 2) + i4;
            if (i < 63) tile[i * 65 + j] = Eb[((size_t)(p0 + i) << 10) + l0 + j];
        }
    }
    __syncthreads();
    {
        int ii = t & 63, jj4 = t >> 6;
        if (ii < 63) {
#pragma unroll
            for (int k = 0; k < 16; ++k) {
                int jj = (k << 2) + jj4;
                out[((size_t)b * NL + l0 + jj) * NP + p0 + ii] = tile[ii * 65 + jj];
            }
        }
    }
}

extern "C" void kernel_launch(void* const* d_in, const int* in_sizes, int n_in,
                              void* d_out, int out_size, void* d_ws, size_t ws_size,
                              hipStream_t stream) {
    const float* f    = (const float*)d_in[0];
    const float* b    = (const float*)d_in[1];
    const float* mask = (const float*)d_in[2];
    float* out = (float*)d_out;

    // Rt lives in d_out (consumed by softmax before transpose overwrites out).
    float* Rt = (float*)d_out;

    // ws layout (floats): E at [16257024 .. 32514048); stats after.
    // A'/B' (82.8 MB) occupy ws from 0 but are dead post-GEMM; E region is
    // written only by softmax (after GEMM completes).
    float* wsf = (float*)d_ws;
    float* E  = wsf + 16257024;
    ushort_t* Ahi = (ushort_t*)d_ws;
    ushort_t* Alo = Ahi + (size_t)NB * A_BSTRIDE;
    ushort_t* Bhi = Alo + (size_t)NB * A_BSTRIDE;
    ushort_t* Blo = Bhi + (size_t)NB * B_BSTRIDE;
    float* invn = wsf + 32514048;
    float* mmk = invn + 256;
    float* mmp = mmk + 4096;

    norm_kernel<<<dim3(256), dim3(256), 0, stream>>>(b, invn);
    stats_kernel<<<dim3(79), dim3(256), 0, stream>>>(mask, mmk, mmp);
    splitA_kernel<<<dim3(32, 4, 2), dim3(256), 0, stream>>>(b, invn, Ahi, Alo);
    splitB_kernel<<<dim3(63, 4, 2), dim3(256), 0, stream>>>(f, Bhi, Blo);
    gemm_kernel<<<dim3(252, 4), dim3(256), 0, stream>>>(Ahi, Alo, Bhi, Blo, Rt);
    softmax_fused_kernel<<<dim3(3969, 4), dim3(256), 0, stream>>>(Rt, mmk, mmp, E);
    transpose_kernel<<<dim3(63, 16, 4), dim3(256), 0, stream>>>(E, out);
}